// Round 2
// baseline (711.042 us; speedup 1.0000x reference)
//
#include <hip/hip_runtime.h>

#define N_NODES 100000
#define N_EDGES 3200000
#define F_IN 128
#define F_OUT 32
#define N_GRAPHS 64

#define SCAN_CHUNK 512
#define N_CHUNKS ((N_NODES + SCAN_CHUNK - 1) / SCAN_CHUNK)   // 196

// ---------------------------------------------------------------------------
// Node transforms xl = x@W_l + b_l ; xr = x@W_r + b_r
// ---------------------------------------------------------------------------
__global__ __launch_bounds__(256) void gat_transform(
    const float* __restrict__ x,
    const float* __restrict__ Wl, const float* __restrict__ bl,
    const float* __restrict__ Wr, const float* __restrict__ br,
    float* __restrict__ xl, float* __restrict__ xr)
{
    __shared__ float sWl[F_IN * F_OUT];
    __shared__ float sWr[F_IN * F_OUT];
    for (int i = threadIdx.x; i < F_IN * F_OUT; i += 256) {
        sWl[i] = Wl[i];
        sWr[i] = Wr[i];
    }
    __syncthreads();

    const int f     = threadIdx.x & 31;
    const int local = threadIdx.x >> 5;
    const int node  = blockIdx.x * 8 + local;
    if (node >= N_NODES) return;

    const float4* xrow = (const float4*)(x + (size_t)node * F_IN);
    float accl = bl[f];
    float accr = br[f];
#pragma unroll
    for (int k4 = 0; k4 < F_IN / 4; ++k4) {
        float4 v = xrow[k4];
        const int k = k4 * 4;
        accl += v.x * sWl[(k + 0) * 32 + f];  accr += v.x * sWr[(k + 0) * 32 + f];
        accl += v.y * sWl[(k + 1) * 32 + f];  accr += v.y * sWr[(k + 1) * 32 + f];
        accl += v.z * sWl[(k + 2) * 32 + f];  accr += v.z * sWr[(k + 2) * 32 + f];
        accl += v.w * sWl[(k + 3) * 32 + f];  accr += v.w * sWr[(k + 3) * 32 + f];
    }
    xl[(size_t)node * 32 + f] = accl;
    xr[(size_t)node * 32 + f] = accr;
}

// ---------------------------------------------------------------------------
// CSR build: histogram of dst, 3-phase exclusive scan, scatter packed edges
// ---------------------------------------------------------------------------
__global__ __launch_bounds__(256) void csr_hist(const int* __restrict__ ei,
                                                int* __restrict__ deg)
{
    const int stride = gridDim.x * blockDim.x;
    for (int e = blockIdx.x * blockDim.x + threadIdx.x; e < N_EDGES; e += stride)
        atomicAdd(&deg[ei[N_EDGES + e]], 1);
}

__global__ __launch_bounds__(256) void csr_scan_partial(const int* __restrict__ deg,
                                                        int* __restrict__ partial)
{
    __shared__ int s[256];
    const int c = blockIdx.x;
    int v = 0;
#pragma unroll
    for (int r = 0; r < SCAN_CHUNK / 256; ++r) {
        const int i = c * SCAN_CHUNK + r * 256 + threadIdx.x;
        if (i < N_NODES) v += deg[i];
    }
    s[threadIdx.x] = v;
    __syncthreads();
    for (int off = 128; off > 0; off >>= 1) {
        if (threadIdx.x < off) s[threadIdx.x] += s[threadIdx.x + off];
        __syncthreads();
    }
    if (threadIdx.x == 0) partial[c] = s[0];
}

__global__ __launch_bounds__(256) void csr_scan_base(const int* __restrict__ partial,
                                                     int* __restrict__ cbase)
{
    __shared__ int s[256];
    const int t = threadIdx.x;
    const int v = (t < N_CHUNKS) ? partial[t] : 0;
    s[t] = v;
    __syncthreads();
    for (int off = 1; off < 256; off <<= 1) {
        int u = (t >= off) ? s[t - off] : 0;
        __syncthreads();
        s[t] += u;
        __syncthreads();
    }
    if (t < N_CHUNKS) cbase[t] = s[t] - v;   // exclusive
}

__global__ __launch_bounds__(256) void csr_scan_write(const int* __restrict__ deg,
                                                      const int* __restrict__ cbase,
                                                      int* __restrict__ rowptr,
                                                      int* __restrict__ wofs)
{
    __shared__ int s[256];
    const int c = blockIdx.x, t = threadIdx.x;
    const int i0 = c * SCAN_CHUNK + 2 * t;
    const int i1 = i0 + 1;
    const int v0 = (i0 < N_NODES) ? deg[i0] : 0;
    const int v1 = (i1 < N_NODES) ? deg[i1] : 0;
    const int pv = v0 + v1;
    s[t] = pv;
    __syncthreads();
    for (int off = 1; off < 256; off <<= 1) {
        int u = (t >= off) ? s[t - off] : 0;
        __syncthreads();
        s[t] += u;
        __syncthreads();
    }
    const int excl = s[t] - pv + cbase[c];
    if (i0 < N_NODES) { rowptr[i0] = excl;      wofs[i0] = excl; }
    if (i1 < N_NODES) { rowptr[i1] = excl + v0; wofs[i1] = excl + v0; }
    if (c == 0 && t == 0) rowptr[N_NODES] = N_EDGES;
}

__global__ __launch_bounds__(256) void csr_scatter(const int* __restrict__ ei,
                                                   const float* __restrict__ eattr,
                                                   int* __restrict__ wofs,
                                                   int2* __restrict__ es2)
{
    const int stride = gridDim.x * blockDim.x;
    for (int e = blockIdx.x * blockDim.x + threadIdx.x; e < N_EDGES; e += stride) {
        const int src = ei[e];
        const int dst = ei[N_EDGES + e];
        const int pos = atomicAdd(&wofs[dst], 1);
        es2[pos] = make_int2(src, __float_as_int(eattr[e]));
    }
}

// ---------------------------------------------------------------------------
// Gather aggregation: one 32-lane group per dst node. No atomics.
// h (output) aliases xr: node n's xr row is read only by its owning group,
// before that group writes h[n]. Single pointer => no restrict violation.
// ---------------------------------------------------------------------------
__global__ __launch_bounds__(256) void gat_aggregate(
    const int2* __restrict__ es2, const int* __restrict__ rowptr,
    const float* __restrict__ We, const float* __restrict__ att,
    const float* __restrict__ xl, float* xrh)
{
    const int f    = threadIdx.x & 31;
    const int node = blockIdx.x * 8 + (threadIdx.x >> 5);
    if (node >= N_NODES) return;

    const float attf = att[f];
    const float wef  = We[f];
    const float xrf  = xrh[(size_t)node * 32 + f];
    const int beg = rowptr[node];
    const int end = rowptr[node + 1];

    float acc = 0.f, den = 0.f;
    for (int j = beg; j < end; ++j) {
        const int2 pe = es2[j];
        const int   src = pe.x;
        const float ea  = __int_as_float(pe.y);
        const float xlv = xl[(size_t)src * 32 + f];
        float m = xlv + xrf + ea * wef;
        m = (m > 0.f) ? m : 0.2f * m;
        float t = m * attf;
        t += __shfl_xor(t, 16, 32);
        t += __shfl_xor(t, 8, 32);
        t += __shfl_xor(t, 4, 32);
        t += __shfl_xor(t, 2, 32);
        t += __shfl_xor(t, 1, 32);
        const float p = __expf(t);
        acc += xlv * p;
        den += p;
    }
    xrh[(size_t)node * 32 + f] = acc / (den + 1e-16f);
}

// ---------------------------------------------------------------------------
// Pool: mean over each graph's node range (batch sorted), + bias.
// ---------------------------------------------------------------------------
__global__ __launch_bounds__(256) void gat_pool(
    const float* __restrict__ h, const float* __restrict__ bias,
    const int* __restrict__ batch, float* __restrict__ out)
{
    const int g = blockIdx.x;
    __shared__ int s_lo, s_hi;
    if (threadIdx.x == 0) {
        int lo = 0, hi = N_NODES;
        while (lo < hi) { int mid = (lo + hi) >> 1; if (batch[mid] < g) lo = mid + 1; else hi = mid; }
        s_lo = lo;
        lo = 0; hi = N_NODES;
        while (lo < hi) { int mid = (lo + hi) >> 1; if (batch[mid] < g + 1) lo = mid + 1; else hi = mid; }
        s_hi = lo;
    }
    __syncthreads();
    const int lo = s_lo, hi = s_hi;

    const int f   = threadIdx.x & 31;
    const int grp = threadIdx.x >> 5;

    float acc = 0.f;
    for (int n = lo + grp; n < hi; n += 8)
        acc += h[(size_t)n * 32 + f];

    __shared__ float s_acc[8][32];
    s_acc[grp][f] = acc;
    __syncthreads();

    if (threadIdx.x < 32) {
        float sum = 0.f;
#pragma unroll
        for (int i = 0; i < 8; ++i) sum += s_acc[i][f];
        const int cnt = hi - lo;
        out[g * 32 + f] = (cnt > 0) ? (sum / (float)cnt + bias[f]) : bias[f];
    }
}

// ---------------------------------------------------------------------------
// Fallback (R1 atomic path) if ws is too small for the CSR layout.
// ---------------------------------------------------------------------------
__global__ __launch_bounds__(256) void gat_edge_atomic(
    const int* __restrict__ ei, const float* __restrict__ eattr,
    const float* __restrict__ We, const float* __restrict__ att,
    const float* __restrict__ xl, const float* __restrict__ xr,
    float* __restrict__ outacc, float* __restrict__ denom)
{
    const int f = threadIdx.x & 31;
    const float attf = att[f];
    const float wef  = We[f];
    const int group   = (blockIdx.x * blockDim.x + threadIdx.x) >> 5;
    const int ngroups = (gridDim.x * blockDim.x) >> 5;
    for (int e = group; e < N_EDGES; e += ngroups) {
        const int src = ei[e];
        const int dst = ei[N_EDGES + e];
        const float xlv = xl[(size_t)src * 32 + f];
        float m = xlv + xr[(size_t)dst * 32 + f] + eattr[e] * wef;
        m = (m > 0.f) ? m : 0.2f * m;
        float t = m * attf;
        t += __shfl_xor(t, 16, 32);
        t += __shfl_xor(t, 8, 32);
        t += __shfl_xor(t, 4, 32);
        t += __shfl_xor(t, 2, 32);
        t += __shfl_xor(t, 1, 32);
        const float p = __expf(t);
        atomicAdd(&outacc[(size_t)dst * 32 + f], xlv * p);
        if (f == 0) atomicAdd(&denom[dst], p);
    }
}

__global__ __launch_bounds__(256) void gat_pool_div(
    const float* __restrict__ outacc, const float* __restrict__ denom,
    const float* __restrict__ bias, const int* __restrict__ batch,
    float* __restrict__ out)
{
    const int g = blockIdx.x;
    __shared__ int s_lo, s_hi;
    if (threadIdx.x == 0) {
        int lo = 0, hi = N_NODES;
        while (lo < hi) { int mid = (lo + hi) >> 1; if (batch[mid] < g) lo = mid + 1; else hi = mid; }
        s_lo = lo;
        lo = 0; hi = N_NODES;
        while (lo < hi) { int mid = (lo + hi) >> 1; if (batch[mid] < g + 1) lo = mid + 1; else hi = mid; }
        s_hi = lo;
    }
    __syncthreads();
    const int lo = s_lo, hi = s_hi;
    const int f   = threadIdx.x & 31;
    const int grp = threadIdx.x >> 5;
    float acc = 0.f;
    for (int n = lo + grp; n < hi; n += 8)
        acc += outacc[(size_t)n * 32 + f] / (denom[n] + 1e-16f);
    __shared__ float s_acc[8][32];
    s_acc[grp][f] = acc;
    __syncthreads();
    if (threadIdx.x < 32) {
        float sum = 0.f;
#pragma unroll
        for (int i = 0; i < 8; ++i) sum += s_acc[i][f];
        const int cnt = hi - lo;
        out[g * 32 + f] = (cnt > 0) ? (sum / (float)cnt + bias[f]) : bias[f];
    }
}

// ---------------------------------------------------------------------------
extern "C" void kernel_launch(void* const* d_in, const int* in_sizes, int n_in,
                              void* d_out, int out_size, void* d_ws, size_t ws_size,
                              hipStream_t stream)
{
    const float* x     = (const float*)d_in[0];
    const float* eattr = (const float*)d_in[1];
    const float* Wl    = (const float*)d_in[2];
    const float* bl    = (const float*)d_in[3];
    const float* Wr    = (const float*)d_in[4];
    const float* br    = (const float*)d_in[5];
    const float* We    = (const float*)d_in[6];
    const float* att   = (const float*)d_in[7];
    const float* bias  = (const float*)d_in[8];
    const int*   ei    = (const int*)d_in[9];
    const int*   batch = (const int*)d_in[10];
    float* out = (float*)d_out;

    float* ws = (float*)d_ws;
    const size_t NF = (size_t)N_NODES * 32;   // 3.2M floats

    // CSR layout: xl | xr(=h) | es2(2*NF... actually N_EDGES int2) | ints
    const size_t need_csr = (NF * 2) * 4 + (size_t)N_EDGES * 8
                          + ((size_t)N_NODES * 2 + 1 + 256) * 4;

    if (ws_size >= need_csr) {
        float* xl  = ws;
        float* xrh = ws + NF;
        int2*  es2 = (int2*)(ws + 2 * NF);
        int*   deg    = (int*)(es2 + N_EDGES);
        int*   rowptr = deg + N_NODES;        // N_NODES+1
        int*   wofs   = rowptr + N_NODES + 1;
        int*   partial = wofs + N_NODES;      // N_CHUNKS
        int*   cbase   = partial;             // reuse in-place via 2nd buffer
        // keep partial and cbase separate to avoid races:
        cbase = partial + 256;

        hipMemsetAsync(deg, 0, N_NODES * sizeof(int), stream);

        csr_hist<<<2048, 256, 0, stream>>>(ei, deg);
        csr_scan_partial<<<N_CHUNKS, 256, 0, stream>>>(deg, partial);
        csr_scan_base<<<1, 256, 0, stream>>>(partial, cbase);
        csr_scan_write<<<N_CHUNKS, 256, 0, stream>>>(deg, cbase, rowptr, wofs);
        csr_scatter<<<2048, 256, 0, stream>>>(ei, eattr, wofs, es2);

        gat_transform<<<(N_NODES + 7) / 8, 256, 0, stream>>>(x, Wl, bl, Wr, br, xl, xrh);
        gat_aggregate<<<(N_NODES + 7) / 8, 256, 0, stream>>>(es2, rowptr, We, att, xl, xrh);
        gat_pool<<<N_GRAPHS, 256, 0, stream>>>(xrh, bias, batch, out);
    } else {
        float* xl     = ws;
        float* xr     = ws + NF;
        float* outacc = ws + 2 * NF;
        float* denom  = ws + 3 * NF;
        hipMemsetAsync(outacc, 0, (NF + N_NODES) * sizeof(float), stream);
        gat_transform<<<(N_NODES + 7) / 8, 256, 0, stream>>>(x, Wl, bl, Wr, br, xl, xr);
        gat_edge_atomic<<<4096, 256, 0, stream>>>(ei, eattr, We, att, xl, xr, outacc, denom);
        gat_pool_div<<<N_GRAPHS, 256, 0, stream>>>(outacc, denom, bias, batch, out);
    }
}